// Round 9
// baseline (196.093 us; speedup 1.0000x reference)
//
#include <hip/hip_runtime.h>
#include <math.h>

#define NN 20000          // nodes
#define EE 320000         // edges
#define KF 128            // IN_F
#define HO 256            // HEADS*OUT_F
#define CAP 96            // slotted-CSR capacity; max Poisson(16) in-degree over 20k nodes ~45

typedef __attribute__((ext_vector_type(8))) short short8;   // 8 bf16 (4 VGPRs)
typedef __attribute__((ext_vector_type(4))) float f32x4;

// ---- bf16 helpers (bit-level, RNE) ----
static __device__ __forceinline__ unsigned short f2bf(float f) {
    union { float f; unsigned u; } v; v.f = f;
    unsigned u = v.u;
    u += 0x7fffu + ((u >> 16) & 1u);
    return (unsigned short)(u >> 16);
}
static __device__ __forceinline__ float bf2f(unsigned short b) {
    union { unsigned u; float f; } v; v.u = ((unsigned)b) << 16;
    return v.f;
}

// ---------------- prep: W->bf16 (once), x->bf16 (once), zero cursor ------------
// grid 2675: [0,96) W convert, [96,2596) x convert, [2596,2675) cursor zero.
__global__ __launch_bounds__(256) void prep_kernel(
    const float* __restrict__ x, const float* __restrict__ W0,
    const float* __restrict__ W1, const float* __restrict__ W2,
    unsigned short* __restrict__ xb, unsigned short* __restrict__ wb,
    int* __restrict__ cursor)
{
    const int b = blockIdx.x;
    const int t = threadIdx.x;
    if (b < 96) {
        const int m = b >> 5;
        const float* __restrict__ Wm = (m == 0) ? W0 : (m == 1) ? W1 : W2;
        int idx = (b & 31) * 1024 + t * 4;
        float4 v = *(const float4*)(Wm + idx);
        ushort4 o;
        o.x = f2bf(v.x); o.y = f2bf(v.y); o.z = f2bf(v.z); o.w = f2bf(v.w);
        *(ushort4*)(wb + (size_t)m * 32768 + idx) = o;
    } else if (b < 2596) {
        size_t i = (size_t)(b - 96) * 1024 + t * 4;     // 2500*1024 = 20000*128 exact
        float4 v = *(const float4*)(x + i);
        ushort4 o;
        o.x = f2bf(v.x); o.y = f2bf(v.y); o.z = f2bf(v.z); o.w = f2bf(v.w);
        *(ushort4*)(xb + i) = o;
    } else {
        int i = (b - 2596) * 256 + t;
        if (i < NN) cursor[i] = 0;
    }
}

// ---------------- slotted-CSR scatter (cursor zeroed by prep) ------------------
__global__ void scatter_kernel(const int* __restrict__ ei, int* __restrict__ cursor,
                               int* __restrict__ csr_src) {
    int e = blockIdx.x * blockDim.x + threadIdx.x;
    if (e < EE) {
        int s = ei[e];
        int d = ei[EE + e];
        int pos = atomicAdd(&cursor[d], 1);
        if (pos < CAP) csr_src[d * CAP + pos] = s;
    }
}

// ---------------- MFMA projection v6: B-in-registers, head-major epilogue ------
// grid (313, 3), 256 thr = 4 waves; wave owns a 64-col strip, B in 64 VGPRs,
// pipelined A loads.  Epilogue scatters bf16 into head-major layouts:
//   m=1 hsrc -> hvh[h][node][0..31]; m=0 values -> hvh[h][node][32..63];
//   m=2 hdst -> hdd[h][node][0..31].
__global__ __launch_bounds__(256, 3) void proj_kernel(
    const unsigned short* __restrict__ xb, const unsigned short* __restrict__ wb,
    unsigned short* __restrict__ hvh, unsigned short* __restrict__ hdd)
{
    const int m = blockIdx.y;
    const unsigned short* __restrict__ Wm = wb + (size_t)m * 32768;

    const int w    = threadIdx.x >> 6;
    const int lane = threadIdx.x & 63;
    const int lr   = lane & 15;
    const int q    = lane >> 4;
    const int cb   = w * 64;                 // this wave's column base

    // ---- B resident in registers: 4 nt x 4 ks x short8 = 64 VGPRs ----
    short8 Bf[4][4];
#pragma unroll
    for (int nt = 0; nt < 4; ++nt)
#pragma unroll
        for (int ks = 0; ks < 4; ++ks)
            Bf[nt][ks] = *(const short8*)(Wm + (size_t)(cb + nt * 16 + lr) * KF + ks * 32 + q * 8);

    const int rb = blockIdx.x * 64;

    short8 Af[4];
    {
        const int arow = rb + lr;
#pragma unroll
        for (int ks = 0; ks < 4; ++ks) {
            Af[ks] = (short8){0,0,0,0,0,0,0,0};
            if (arow < NN)
                Af[ks] = *(const short8*)(xb + (size_t)arow * KF + ks * 32 + q * 8);
        }
    }

#pragma unroll
    for (int it = 0; it < 4; ++it) {
        const int r0 = rb + it * 16;

        short8 An[4];
        if (it < 3) {
            const int arow = r0 + 16 + lr;
#pragma unroll
            for (int ks = 0; ks < 4; ++ks) {
                An[ks] = (short8){0,0,0,0,0,0,0,0};
                if (arow < NN)
                    An[ks] = *(const short8*)(xb + (size_t)arow * KF + ks * 32 + q * 8);
            }
        }

        f32x4 acc[4];
#pragma unroll
        for (int nt = 0; nt < 4; ++nt) acc[nt] = (f32x4){0.f, 0.f, 0.f, 0.f};

#pragma unroll
        for (int ks = 0; ks < 4; ++ks)
#pragma unroll
            for (int nt = 0; nt < 4; ++nt)
                acc[nt] = __builtin_amdgcn_mfma_f32_16x16x32_bf16(Af[ks], Bf[nt][ks], acc[nt], 0, 0, 0);

#pragma unroll
        for (int nt = 0; nt < 4; ++nt) {
            const int col = cb + nt * 16 + lr;         // 0..255
            const int h   = col >> 5;
            const int f   = col & 31;
            // head-major base for this column
            const size_t cbase = (m == 2)
                ? ((size_t)h * NN) * 32 + f
                : ((size_t)h * NN) * 64 + f + (m == 0 ? 32 : 0);
            unsigned short* __restrict__ outp = (m == 2) ? hdd : hvh;
            const int rowmul = (m == 2) ? 32 : 64;
#pragma unroll
            for (int r = 0; r < 4; ++r) {
                const int row = r0 + q * 4 + r;
                if (row < NN)
                    outp[cbase + (size_t)row * rowmul] = f2bf(acc[nt][r]);
            }
        }

        if (it < 3) {
#pragma unroll
            for (int ks = 0; ks < 4; ++ks) Af[ks] = An[ks];
        }
    }
}

// ---------------- main GAT v3: head-partitioned, XCD-swizzled ------------------
// head = blockIdx.x & 7 (round-robin block->XCD => each XCD works one head,
// whose hvh slice is 2.56 MB and fits its 4 MB L2).  Block = 4 waves = 4 dst
// nodes for that head.  Within a wave: 8 edges in parallel, 8 lanes per edge
// (lanes r=0..3 compute the 32-feat logit, r=4..7 accumulate values).
__global__ __launch_bounds__(256) void gat_kernel(
    const unsigned short* __restrict__ hvh, const unsigned short* __restrict__ hdd,
    const float* __restrict__ att, const float* __restrict__ bias,
    const int* __restrict__ cursor, const int* __restrict__ csr_src,
    float* __restrict__ out)
{
    const int bx   = blockIdx.x;
    const int h    = bx & 7;                  // XCD-aware swizzle
    const int grp  = bx >> 3;
    const int w    = threadIdx.x >> 6;
    const int d    = grp * 4 + w;             // 20000 = 5000*4 exact
    const int lane = threadIdx.x & 63;
    const int slot = lane >> 3;               // 8 parallel edges
    const int r    = lane & 7;                // 0..3: hs-lanes, 4..7: v-lanes
    const int f8   = (r & 3) * 8;             // this lane's 8-feature slice

    float a[8];
    {
        const float4 aa = *(const float4*)(att + h * 32 + f8);
        const float4 ab = *(const float4*)(att + h * 32 + f8 + 4);
        a[0] = aa.x; a[1] = aa.y; a[2] = aa.z; a[3] = aa.w;
        a[4] = ab.x; a[5] = ab.y; a[6] = ab.z; a[7] = ab.w;
    }
    float hd[8];
    {
        const short8 h8 = *(const short8*)(hdd + ((size_t)h * NN + d) * 32 + f8);
#pragma unroll
        for (int j = 0; j < 8; ++j) hd[j] = bf2f((unsigned short)h8[j]);
    }

    int deg = cursor[d];
    if (deg > CAP) deg = CAP;

    // preload up to 64 edge srcs; broadcast via shfl (same index across a group)
    int sreg = (lane < deg) ? csr_src[d * CAP + lane] : 0;

    float l = 0.f;
    float o[8] = {0.f, 0.f, 0.f, 0.f, 0.f, 0.f, 0.f, 0.f};
    const size_t hbase = (size_t)h * NN;

#define EDGE_BODY(SVAL, EIDX)                                                 \
    {                                                                         \
        const short8 x8 = *(const short8*)(hvh + (hbase + (SVAL)) * 64 + r * 8); \
        float pp = 0.f;                                                       \
        _Pragma("unroll")                                                     \
        for (int j = 0; j < 8; ++j) {                                         \
            float z = bf2f((unsigned short)x8[j]) + hd[j];                    \
            z = fmaxf(z, 0.2f * z);                                           \
            pp = fmaf(a[j], z, pp);                                           \
        }                                                                     \
        pp += __shfl_xor(pp, 1);                                              \
        pp += __shfl_xor(pp, 2);                                              \
        const float pv = __shfl_xor(pp, 4);   /* v-lanes get hs-quad logit */ \
        const float e = ((EIDX) < deg) ? __expf(pv) : 0.f;                    \
        l += e;                                                               \
        _Pragma("unroll")                                                     \
        for (int j = 0; j < 8; ++j)                                           \
            o[j] = fmaf(e, bf2f((unsigned short)x8[j]), o[j]);                \
    }

    const int niter = (deg + 7) >> 3;
    const int nfast = (niter < 8) ? niter : 8;
#pragma unroll 2
    for (int it = 0; it < nfast; ++it) {
        const int ei = it * 8 + slot;
        const int s  = __shfl(sreg, ei);
        EDGE_BODY(s, ei);
    }
    for (int it = 8; it < niter; ++it) {      // deg > 64: essentially never
        const int ei = it * 8 + slot;
        const int s  = (ei < deg) ? csr_src[d * CAP + ei] : 0;
        EDGE_BODY(s, ei);
    }
#undef EDGE_BODY

    // reduce across the 8 slots (lane stride 8 preserves r)
    l += __shfl_xor(l, 8); l += __shfl_xor(l, 16); l += __shfl_xor(l, 32);
#pragma unroll
    for (int j = 0; j < 8; ++j) {
        o[j] += __shfl_xor(o[j], 8);
        o[j] += __shfl_xor(o[j], 16);
        o[j] += __shfl_xor(o[j], 32);
    }

    if (r >= 4) {                             // v-lanes hold the output
        const float inv = (deg > 0) ? 1.f / l : 0.f;
        const int fb = h * 32 + f8;
        const float4 b0 = *(const float4*)(bias + fb);
        const float4 b1 = *(const float4*)(bias + fb + 4);
        float4 r0, r1;
        r0.x = o[0] * inv + b0.x; r0.y = o[1] * inv + b0.y;
        r0.z = o[2] * inv + b0.z; r0.w = o[3] * inv + b0.w;
        r1.x = o[4] * inv + b1.x; r1.y = o[5] * inv + b1.y;
        r1.z = o[6] * inv + b1.z; r1.w = o[7] * inv + b1.w;
        *(float4*)(out + (size_t)d * HO + fb) = r0;
        *(float4*)(out + (size_t)d * HO + fb + 4) = r1;
    }
}

extern "C" void kernel_launch(void* const* d_in, const int* in_sizes, int n_in,
                              void* d_out, int out_size, void* d_ws, size_t ws_size,
                              hipStream_t stream) {
    const float* x    = (const float*)d_in[0];
    const int*   ei   = (const int*)d_in[1];
    const float* W0   = (const float*)d_in[2];
    const float* W1   = (const float*)d_in[3];
    const float* W2   = (const float*)d_in[4];
    const float* att  = (const float*)d_in[5];
    const float* bias = (const float*)d_in[6];
    float* out = (float*)d_out;

    char* p = (char*)d_ws;
    unsigned short* hvh = (unsigned short*)p; p += (size_t)8 * NN * 64 * 2;  // [h][node][hs|v]
    unsigned short* hdd = (unsigned short*)p; p += (size_t)8 * NN * 32 * 2;  // [h][node][hdst]
    unsigned short* xb  = (unsigned short*)p; p += (size_t)NN * KF * 2;
    unsigned short* wb  = (unsigned short*)p; p += (size_t)3 * 32768 * 2;
    int* cursor  = (int*)p; p += (size_t)NN * sizeof(int);
    int* csr_src = (int*)p; p += (size_t)NN * CAP * sizeof(int);

    prep_kernel<<<2675, 256, 0, stream>>>(x, W0, W1, W2, xb, wb, cursor);
    scatter_kernel<<<(EE + 255) / 256, 256, 0, stream>>>(ei, cursor, csr_src);
    proj_kernel<<<dim3(313, 3), 256, 0, stream>>>(xb, wb, hvh, hdd);
    gat_kernel<<<8 * (NN / 4), 256, 0, stream>>>(hvh, hdd, att, bias, cursor, csr_src, out);
}

// Round 10
// 191.060 us; speedup vs baseline: 1.0263x; 1.0263x over previous
//
#include <hip/hip_runtime.h>
#include <math.h>

#define NN 20000          // nodes
#define EE 320000         // edges
#define KF 128            // IN_F
#define HO 256            // HEADS*OUT_F
#define CAP 96            // slotted-CSR capacity; max Poisson(16) in-degree over 20k nodes ~45

typedef __attribute__((ext_vector_type(8))) short short8;   // 8 bf16 (4 VGPRs)
typedef __attribute__((ext_vector_type(4))) float f32x4;

// ---- bf16 helpers (bit-level, RNE) ----
static __device__ __forceinline__ unsigned short f2bf(float f) {
    union { float f; unsigned u; } v; v.f = f;
    unsigned u = v.u;
    u += 0x7fffu + ((u >> 16) & 1u);
    return (unsigned short)(u >> 16);
}
static __device__ __forceinline__ float bf2f(unsigned short b) {
    union { unsigned u; float f; } v; v.u = ((unsigned)b) << 16;
    return v.f;
}
static __device__ __forceinline__ float bfbits2f(unsigned u) {   // u = bf16 bits in low 16
    union { unsigned u; float f; } v; v.u = u << 16;
    return v.f;
}

// ---------------- prep: W->bf16 (once), x->bf16 (once), zero cursor ------------
// grid 2675: [0,96) W convert, [96,2596) x convert, [2596,2675) cursor zero.
__global__ __launch_bounds__(256) void prep_kernel(
    const float* __restrict__ x, const float* __restrict__ W0,
    const float* __restrict__ W1, const float* __restrict__ W2,
    unsigned short* __restrict__ xb, unsigned short* __restrict__ wb,
    int* __restrict__ cursor)
{
    const int b = blockIdx.x;
    const int t = threadIdx.x;
    if (b < 96) {
        const int m = b >> 5;
        const float* __restrict__ Wm = (m == 0) ? W0 : (m == 1) ? W1 : W2;
        int idx = (b & 31) * 1024 + t * 4;
        float4 v = *(const float4*)(Wm + idx);
        ushort4 o;
        o.x = f2bf(v.x); o.y = f2bf(v.y); o.z = f2bf(v.z); o.w = f2bf(v.w);
        *(ushort4*)(wb + (size_t)m * 32768 + idx) = o;
    } else if (b < 2596) {
        size_t i = (size_t)(b - 96) * 1024 + t * 4;     // 2500*1024 = 20000*128 exact
        float4 v = *(const float4*)(x + i);
        ushort4 o;
        o.x = f2bf(v.x); o.y = f2bf(v.y); o.z = f2bf(v.z); o.w = f2bf(v.w);
        *(ushort4*)(xb + i) = o;
    } else {
        int i = (b - 2596) * 256 + t;
        if (i < NN) cursor[i] = 0;
    }
}

// ---------------- slotted-CSR scatter (cursor zeroed by prep) ------------------
__global__ void scatter_kernel(const int* __restrict__ ei, int* __restrict__ cursor,
                               int* __restrict__ csr_src) {
    int e = blockIdx.x * blockDim.x + threadIdx.x;
    if (e < EE) {
        int s = ei[e];
        int d = ei[EE + e];
        int pos = atomicAdd(&cursor[d], 1);
        if (pos < CAP) csr_src[d * CAP + pos] = s;
    }
}

// ---------------- MFMA projection v6: B-in-registers, head-major epilogue ------
__global__ __launch_bounds__(256, 3) void proj_kernel(
    const unsigned short* __restrict__ xb, const unsigned short* __restrict__ wb,
    unsigned short* __restrict__ hvh, unsigned short* __restrict__ hdd)
{
    const int m = blockIdx.y;
    const unsigned short* __restrict__ Wm = wb + (size_t)m * 32768;

    const int w    = threadIdx.x >> 6;
    const int lane = threadIdx.x & 63;
    const int lr   = lane & 15;
    const int q    = lane >> 4;
    const int cb   = w * 64;                 // this wave's column base

    short8 Bf[4][4];
#pragma unroll
    for (int nt = 0; nt < 4; ++nt)
#pragma unroll
        for (int ks = 0; ks < 4; ++ks)
            Bf[nt][ks] = *(const short8*)(Wm + (size_t)(cb + nt * 16 + lr) * KF + ks * 32 + q * 8);

    const int rb = blockIdx.x * 64;

    short8 Af[4];
    {
        const int arow = rb + lr;
#pragma unroll
        for (int ks = 0; ks < 4; ++ks) {
            Af[ks] = (short8){0,0,0,0,0,0,0,0};
            if (arow < NN)
                Af[ks] = *(const short8*)(xb + (size_t)arow * KF + ks * 32 + q * 8);
        }
    }

#pragma unroll
    for (int it = 0; it < 4; ++it) {
        const int r0 = rb + it * 16;

        short8 An[4];
        if (it < 3) {
            const int arow = r0 + 16 + lr;
#pragma unroll
            for (int ks = 0; ks < 4; ++ks) {
                An[ks] = (short8){0,0,0,0,0,0,0,0};
                if (arow < NN)
                    An[ks] = *(const short8*)(xb + (size_t)arow * KF + ks * 32 + q * 8);
            }
        }

        f32x4 acc[4];
#pragma unroll
        for (int nt = 0; nt < 4; ++nt) acc[nt] = (f32x4){0.f, 0.f, 0.f, 0.f};

#pragma unroll
        for (int ks = 0; ks < 4; ++ks)
#pragma unroll
            for (int nt = 0; nt < 4; ++nt)
                acc[nt] = __builtin_amdgcn_mfma_f32_16x16x32_bf16(Af[ks], Bf[nt][ks], acc[nt], 0, 0, 0);

#pragma unroll
        for (int nt = 0; nt < 4; ++nt) {
            const int col = cb + nt * 16 + lr;         // 0..255
            const int h   = col >> 5;
            const int f   = col & 31;
            const size_t cbase = (m == 2)
                ? ((size_t)h * NN) * 32 + f
                : ((size_t)h * NN) * 64 + f + (m == 0 ? 32 : 0);
            unsigned short* __restrict__ outp = (m == 2) ? hdd : hvh;
            const int rowmul = (m == 2) ? 32 : 64;
#pragma unroll
            for (int r = 0; r < 4; ++r) {
                const int row = r0 + q * 4 + r;
                if (row < NN)
                    outp[cbase + (size_t)row * rowmul] = f2bf(acc[nt][r]);
            }
        }

        if (it < 3) {
#pragma unroll
            for (int ks = 0; ks < 4; ++ks) Af[ks] = An[ks];
        }
    }
}

// ---------------- main GAT v4: head-partitioned, two-phase, low overhead -------
// head = blockIdx.x & 7 (XCD swizzle; per-head slice 3.8 MB fits 4 MB L2).
// Wave = one (dst, head).  Phase 1: 16 edges/iter, 4 lanes x 8 hs-elems per
// edge compute logits; e stored in registers (masked 0 for pads).  Phase 2:
// lanes remap to 4 copies x 16 elem-pairs; per k-step 4 edges accumulate via
// packed ushort2 v-loads.  Final reduce: only {l,o0,o1} x 2 shfl levels.
__global__ __launch_bounds__(256) void gat_kernel(
    const unsigned short* __restrict__ hvh, const unsigned short* __restrict__ hdd,
    const float* __restrict__ att, const float* __restrict__ bias,
    const int* __restrict__ cursor, const int* __restrict__ csr_src,
    float* __restrict__ out)
{
    const int bx   = blockIdx.x;
    const int h    = bx & 7;                  // XCD-aware swizzle
    const int grp  = bx >> 3;
    const int w    = threadIdx.x >> 6;
    const int d    = grp * 4 + w;             // 20000 = 5000*4 exact
    const int lane = threadIdx.x & 63;
    const int s4   = lane >> 2;               // phase-1 slot: 16 parallel edges
    const int r4   = lane & 3;                // phase-1 8-elem slice of hs
    const int c    = lane >> 4;               // phase-2 copy (edge subset)
    const int pp   = lane & 15;               // phase-2 elem pair (feats 2pp,2pp+1)

    const unsigned short* __restrict__ hb = hvh + (size_t)h * NN * 64;

    float a[8];
    {
        const float4 aa = *(const float4*)(att + h * 32 + r4 * 8);
        const float4 ab = *(const float4*)(att + h * 32 + r4 * 8 + 4);
        a[0] = aa.x; a[1] = aa.y; a[2] = aa.z; a[3] = aa.w;
        a[4] = ab.x; a[5] = ab.y; a[6] = ab.z; a[7] = ab.w;
    }
    float hd[8];
    {
        const short8 h8 = *(const short8*)(hdd + ((size_t)h * NN + d) * 32 + r4 * 8);
#pragma unroll
        for (int j = 0; j < 8; ++j) hd[j] = bf2f((unsigned short)h8[j]);
    }

    int deg = cursor[d];
    if (deg > CAP) deg = CAP;
    const int ng = (deg + 15) >> 4;           // 16-edge groups (<= 6)

    // preload first 64 edge srcs; broadcast via shfl
    int sreg = (lane < deg) ? csr_src[d * CAP + lane] : 0;

    // ---- Phase 1: logits -> e_reg[it] (0 for pad edges) ----
    float e_reg[6];
#pragma unroll
    for (int it = 0; it < 6; ++it) e_reg[it] = 0.f;

#pragma unroll
    for (int it = 0; it < 6; ++it) {
        if (it < ng) {
            const int i = it * 16 + s4;
            int sv;
            if (it < 4) sv = __shfl(sreg, i);
            else        sv = (i < deg) ? csr_src[d * CAP + i] : 0;
            const short8 x8 = *(const short8*)(hb + (size_t)sv * 64 + r4 * 8);
            float p = 0.f;
#pragma unroll
            for (int j = 0; j < 8; ++j) {
                float z = bf2f((unsigned short)x8[j]) + hd[j];
                z = fmaxf(z, 0.2f * z);
                p = fmaf(a[j], z, p);
            }
            p += __shfl_xor(p, 1);
            p += __shfl_xor(p, 2);
            e_reg[it] = (i < deg) ? __expf(p) : 0.f;
        }
    }

    // ---- Phase 2: weighted accumulation (4 copies x 16 elem-pairs) ----
    float l = 0.f, o0 = 0.f, o1 = 0.f;
#pragma unroll
    for (int it = 0; it < 6; ++it) {
        if (it < ng) {
            const float eg = e_reg[it];
#pragma unroll
            for (int k = 0; k < 4; ++k) {
                const int j = c * 4 + k;          // group-local edge 0..15
                const int i = it * 16 + j;
                int sv;
                if (it < 4) sv = __shfl(sreg, i);
                else        sv = (i < deg) ? csr_src[d * CAP + i] : 0;
                const float ew = __shfl(eg, j * 4);   // e==0 for pad edges
                const unsigned v2 = *(const unsigned*)(hb + (size_t)sv * 64 + 32 + pp * 2);
                o0 = fmaf(ew, bfbits2f(v2 & 0xffffu), o0);
                o1 = fmaf(ew, bfbits2f(v2 >> 16), o1);
                l += ew;
            }
        }
    }

    // ---- reduce over the 4 copies (lane bits 4,5) ----
    l  += __shfl_xor(l, 16);   l  += __shfl_xor(l, 32);
    o0 += __shfl_xor(o0, 16);  o0 += __shfl_xor(o0, 32);
    o1 += __shfl_xor(o1, 16);  o1 += __shfl_xor(o1, 32);

    if (lane < 16) {                          // copy 0 writes features 2pp,2pp+1
        const float inv = (deg > 0) ? 1.f / l : 0.f;
        const int fb = h * 32 + pp * 2;
        const float2 bb = *(const float2*)(bias + fb);
        float2 res;
        res.x = o0 * inv + bb.x;
        res.y = o1 * inv + bb.y;
        *(float2*)(out + (size_t)d * HO + fb) = res;
    }
}

extern "C" void kernel_launch(void* const* d_in, const int* in_sizes, int n_in,
                              void* d_out, int out_size, void* d_ws, size_t ws_size,
                              hipStream_t stream) {
    const float* x    = (const float*)d_in[0];
    const int*   ei   = (const int*)d_in[1];
    const float* W0   = (const float*)d_in[2];
    const float* W1   = (const float*)d_in[3];
    const float* W2   = (const float*)d_in[4];
    const float* att  = (const float*)d_in[5];
    const float* bias = (const float*)d_in[6];
    float* out = (float*)d_out;

    char* p = (char*)d_ws;
    unsigned short* hvh = (unsigned short*)p; p += (size_t)8 * NN * 64 * 2;  // [h][node][hs|v]
    unsigned short* hdd = (unsigned short*)p; p += (size_t)8 * NN * 32 * 2;  // [h][node][hdst]
    unsigned short* xb  = (unsigned short*)p; p += (size_t)NN * KF * 2;
    unsigned short* wb  = (unsigned short*)p; p += (size_t)3 * 32768 * 2;
    int* cursor  = (int*)p; p += (size_t)NN * sizeof(int);
    int* csr_src = (int*)p; p += (size_t)NN * CAP * sizeof(int);

    prep_kernel<<<2675, 256, 0, stream>>>(x, W0, W1, W2, xb, wb, cursor);
    scatter_kernel<<<(EE + 255) / 256, 256, 0, stream>>>(ei, cursor, csr_src);
    proj_kernel<<<dim3(313, 3), 256, 0, stream>>>(xb, wb, hvh, hdd);
    gat_kernel<<<8 * (NN / 4), 256, 0, stream>>>(hvh, hdd, att, bias, cursor, csr_src, out);
}